// Round 10
// baseline (36.695 us; speedup 1.0000x reference)
//
#include <hip/hip_runtime.h>

#define BATCH 16
#define NCLS 80
#define FH 128
#define FW 128
#define HW (FH*FW)
#define MAXO 100
#define NOBJ (BATCH*MAXO)

#define NB1 2048                       // streaming blocks
#define F4TOT (BATCH*NCLS*HW/4)        // 5,242,880 float4
#define F4BLK (F4TOT/NB1)              // 2560 float4 per block (contiguous)
#define F4THR (F4BLK/256)              // 10 float4 per thread
#define NREG (NOBJ/64)                 // 25 reg-gather blocks (64 obj each)
#define NSMALL (NOBJ + NREG)           // small blocks go FIRST (no tail)
#define NBLK (NSMALL + NB1)

__device__ __forceinline__ float smooth_l1(float x) {
    const float F = 1.0f/9.0f;
    return (x >= F) ? (x - 0.5f*F) : (0.5f*x*x/F);
}

__device__ __forceinline__ float bg_term(float h) {
    float p = fminf(fmaxf(h, 1.0e-4f), 1.0f - 1.0e-4f);
    return -__logf(1.0f - p) * p * p;
}

// Gaussian params for one annotation row (zeros + cls=-1 if invalid).
__device__ __forceinline__ void obj_gauss(const float* a, float& cxi, float& cyi,
                                          float& r, float& coef, int& cls) {
    float clsf = a[4];
    if (!(clsf >= 0.0f)) { cls = -1; cxi = cyi = r = 0.0f; coef = -1.0f; return; }
    cls = (int)clsf;
    float x1 = fminf(fmaxf(a[0]*0.25f, 0.0f), (float)(FW-1));
    float y1 = fminf(fmaxf(a[1]*0.25f, 0.0f), (float)(FH-1));
    float x2 = fminf(fmaxf(a[2]*0.25f, 0.0f), (float)(FW-1));
    float y2 = fminf(fmaxf(a[3]*0.25f, 0.0f), (float)(FH-1));
    float bw = x2 - x1, bh = y2 - y1;
    cxi = truncf((x1 + x2)*0.5f);
    cyi = truncf((y1 + y2)*0.5f);
    float h = ceilf(bh), w = ceilf(bw);
    const float MO = 0.7f;
    float b1 = h + w;
    float c1 = w*h*(1.0f - MO)/(1.0f + MO);
    float r1 = (b1 + sqrtf(b1*b1 - 4.0f*c1))*0.5f;
    float b2 = 2.0f*(h + w);
    float c2 = (1.0f - MO)*w*h;
    float r2 = (b2 + sqrtf(b2*b2 - 16.0f*c2))*0.5f;
    float a3 = 4.0f*MO;
    float b3 = -2.0f*MO*(h + w);
    float c3 = (MO - 1.0f)*w*h;
    float r3 = (b3 + sqrtf(b3*b3 - 4.0f*a3*c3))/(2.0f*a3);
    r = fmaxf(0.0f, truncf(fminf(fminf(r1, r2), r3)));
    float sigma = (2.0f*r + 1.0f)/6.0f;
    coef = -1.0f/(2.0f*sigma*sigma);
}

// blk < NOBJ            : per-object focal correction          -> (acc, pnum, 0)
// NOBJ <= blk < NSMALL  : 64-object smooth-L1 gather           -> (loff, lwh, n)
// blk >= NSMALL         : background stream over 2560 float4   -> (acc, 0, 0)
//                         + a second laundered probe pass (measurement only)
__launch_bounds__(256)
__global__ void focal_kernel(const float4* __restrict__ heat,
                             const float*  __restrict__ annot,
                             const float*  __restrict__ offp,
                             const float*  __restrict__ whp,
                             float4*       __restrict__ part)
{
    int blk = blockIdx.x;
    int tid = threadIdx.x;
    __shared__ float sx[MAXO], sy[MAXO], sr[MAXO], sk[MAXO];
    __shared__ int scls[MAXO];
    __shared__ float wred[3][4];

    float v0 = 0.0f, v1 = 0.0f, v2 = 0.0f;

    if (blk >= NSMALL) {
        // ---- background stream with explicit 2-deep prefetch pipeline ----
        const float4* hp = heat + (size_t)(blk - NSMALL)*F4BLK + tid;
        float4 cur = hp[0];
        #pragma unroll
        for (int i = 0; i < F4THR; ++i) {
            float4 nxt = make_float4(0.f, 0.f, 0.f, 0.f);
            if (i + 1 < F4THR) nxt = hp[(i+1)*256];   // issue next load early
            v0 += bg_term(cur.x) + bg_term(cur.y) + bg_term(cur.z) + bg_term(cur.w);
            cur = nxt;
        }
        // ---- MEASUREMENT PASS: re-stream same slab via laundered pointer ----
        // (loads can't be CSE'd with pass 1; result sunk into asm, no output
        //  effect; dur_us delta vs R8 == warm memory-stream time for 84 MB)
        {
            uintptr_t praw = (uintptr_t)hp;
            asm volatile("" : "+v"(praw));            // launder: kill CSE/alias info
            const float4* hp2 = (const float4*)praw;
            float probe = 0.0f;
            #pragma unroll
            for (int i = 0; i < F4THR; ++i) {
                float4 h4 = hp2[i*256];
                probe += h4.x + h4.y + h4.z + h4.w;
            }
            asm volatile("" :: "v"(probe));           // keep loads live
        }
    } else if (blk < NOBJ) {
        // ---- per-object correction ----
        int o = blk;
        int b = o / MAXO;
        int oi = o - b*MAXO;
        if (tid < MAXO) {
            const float* a = annot + ((size_t)b*MAXO + tid)*5;
            float cxi, cyi, r, coef; int cls;
            obj_gauss(a, cxi, cyi, r, coef, cls);
            sx[tid] = cxi; sy[tid] = cyi; sr[tid] = r; sk[tid] = coef; scls[tid] = cls;
        }
        __syncthreads();
        int c = scls[oi];
        if (c >= 0) {
            int cxo = (int)sx[oi], cyo = (int)sy[oi];
            int r = (int)sr[oi];
            int side = 2*r + 1;
            int npx = side*side;
            const float* hc = (const float*)heat + (size_t)(b*NCLS + c)*HW;
            for (int pi = tid; pi < npx; pi += 256) {
                int px = cxo - r + (pi % side);
                int py = cyo - r + (pi / side);
                if (px < 0 || px >= FW || py < 0 || py >= FH) continue;
                float fpx = (float)px, fpy = (float)py;
                float gmax = 0.0f;
                bool owner = true;
                for (int j = 0; j < MAXO; ++j) {
                    if (scls[j] != c) continue;
                    float dx = fpx - sx[j], dy = fpy - sy[j];
                    if (fabsf(dx) <= sr[j] && fabsf(dy) <= sr[j]) {
                        if (j < oi) { owner = false; break; }
                        gmax = fmaxf(gmax, __expf(sk[j]*(dx*dx + dy*dy)));
                    }
                }
                if (!owner) continue;
                float h = hc[py*FW + px];
                float p = fminf(fmaxf(h, 1.0e-4f), 1.0f - 1.0e-4f);
                float bg = -__logf(1.0f - p) * p * p;   // bitwise == streaming term
                if (gmax == 1.0f) {
                    float om = 1.0f - p;
                    v0 += -__logf(p)*om*om - bg;
                    v1 += 1.0f;
                } else {
                    float og = 1.0f - gmax;
                    float w2 = og*og;
                    v0 += bg*(w2*w2 - 1.0f);
                }
            }
        }
    } else {
        // ---- 64-object smooth-L1 gather ----
        int rb = blk - NOBJ;
        if (tid < 64) {
            int o = rb*64 + tid;
            int b = o / MAXO;
            const float* a = annot + (size_t)o*5;
            float clsf = a[4];
            float m = (clsf >= 0.0f) ? 1.0f : 0.0f;
            float x1 = fminf(fmaxf(a[0]*0.25f, 0.0f), (float)(FW-1));
            float y1 = fminf(fmaxf(a[1]*0.25f, 0.0f), (float)(FH-1));
            float x2 = fminf(fmaxf(a[2]*0.25f, 0.0f), (float)(FW-1));
            float y2 = fminf(fmaxf(a[3]*0.25f, 0.0f), (float)(FH-1));
            float cx = (x1 + x2)*0.5f, cy = (y1 + y2)*0.5f;
            float cxi = truncf(cx), cyi = truncf(cy);
            float tx = (cx - cxi)*m, ty = (cy - cyi)*m;
            float tw = (x2 - x1)*m, th = (y2 - y1)*m;
            int idx = (int)((cyi*(float)FW + cxi)*m);
            const float* ob = offp + (size_t)b*2*HW;
            const float* wb = whp  + (size_t)b*2*HW;
            float p0 = ob[idx], p1 = ob[HW + idx];
            float q0 = wb[idx], q1 = wb[HW + idx];
            v0 = smooth_l1(fabsf(p0*m - tx*m)) + smooth_l1(fabsf(p1*m - ty*m));
            v1 = smooth_l1(fabsf(q0*m - tw*m)) + smooth_l1(fabsf(q1*m - th*m));
            v2 = m;
        }
    }

    #pragma unroll
    for (int off = 32; off > 0; off >>= 1) {
        v0 += __shfl_down(v0, off);
        v1 += __shfl_down(v1, off);
        v2 += __shfl_down(v2, off);
    }
    int lane = tid & 63, wid = tid >> 6;
    if (lane == 0) { wred[0][wid] = v0; wred[1][wid] = v1; wred[2][wid] = v2; }
    __syncthreads();
    if (tid == 0) {
        float A = 0.0f, B2 = 0.0f, C2 = 0.0f;
        #pragma unroll
        for (int i = 0; i < 4; ++i) { A += wred[0][i]; B2 += wred[1][i]; C2 += wred[2][i]; }
        part[blk] = make_float4(A, B2, C2, 0.0f);
    }
}

// Final combine: reduce all partials, apply normalizations. One block.
__launch_bounds__(256)
__global__ void finalize_kernel(const float4* __restrict__ part,
                                float*        __restrict__ out)
{
    float P = 0.0f, Q = 0.0f;           // focal acc, pos_num
    float LO = 0.0f, LW = 0.0f, NN = 0.0f;
    // corrections [0,NOBJ) and streaming [NSMALL,NBLK) carry (acc,pnum)
    for (int i = threadIdx.x; i < NOBJ; i += blockDim.x) {
        float4 v = part[i];
        P += v.x; Q += v.y;
    }
    for (int i = NSMALL + threadIdx.x; i < NBLK; i += blockDim.x) {
        float4 v = part[i];
        P += v.x; Q += v.y;
    }
    // reg blocks [NOBJ,NSMALL) carry (loff,lwh,n)
    for (int i = NOBJ + threadIdx.x; i < NSMALL; i += blockDim.x) {
        float4 v = part[i];
        LO += v.x; LW += v.y; NN += v.z;
    }
    __shared__ float wred[5][4];
    #pragma unroll
    for (int off = 32; off > 0; off >>= 1) {
        P  += __shfl_down(P,  off);
        Q  += __shfl_down(Q,  off);
        LO += __shfl_down(LO, off);
        LW += __shfl_down(LW, off);
        NN += __shfl_down(NN, off);
    }
    int lane = threadIdx.x & 63, wid = threadIdx.x >> 6;
    if (lane == 0) {
        wred[0][wid] = P; wred[1][wid] = Q;
        wred[2][wid] = LO; wred[3][wid] = LW; wred[4][wid] = NN;
    }
    __syncthreads();
    if (threadIdx.x == 0) {
        float s[5];
        #pragma unroll
        for (int r = 0; r < 5; ++r) {
            s[r] = wred[r][0] + wred[r][1] + wred[r][2] + wred[r][3];
        }
        float pn = s[1];
        float hm = (pn > 0.0f) ? s[0]/fmaxf(pn, 1.0f) : 0.0f;
        float ol = (s[4] > 0.0f) ? s[2]/fmaxf(s[4], 1.0f) : 0.0f;
        float wl = (s[4] > 0.0f) ? s[3]/fmaxf(s[4], 1.0f) : 0.0f;
        out[0] = 1.0f*hm;   // HM_W
        out[1] = 1.0f*ol;   // OFF_W
        out[2] = 0.1f*wl;   // WH_W
    }
}

extern "C" void kernel_launch(void* const* d_in, const int* in_sizes, int n_in,
                              void* d_out, int out_size, void* d_ws, size_t ws_size,
                              hipStream_t stream) {
    const float* heat  = (const float*)d_in[0];  // (16,80,128,128)
    const float* offp  = (const float*)d_in[1];  // (16,2,128,128)
    const float* whp   = (const float*)d_in[2];  // (16,2,128,128)
    const float* annot = (const float*)d_in[3];  // (16,100,5)
    float* out = (float*)d_out;                  // (3,)

    float4* part = (float4*)d_ws;                // NBLK partials

    focal_kernel<<<NBLK, 256, 0, stream>>>((const float4*)heat, annot, offp, whp, part);
    finalize_kernel<<<1, 256, 0, stream>>>(part, out);
}